// Round 12
// baseline (226.829 us; speedup 1.0000x reference)
//
#include <hip/hip_runtime.h>
#include <math.h>

#define N_NODES 4096
#define NROWS   8192      // both sides stacked
#define BGRAPH  32
#define NEDGE   65536
#define DIM     128
#define NLAYER  4
#define NHEAD   4
#define DHEAD   32
#define QDIM    384       // 3*DIM

typedef _Float16 half8v __attribute__((ext_vector_type(8)));
typedef _Float16 half4v __attribute__((ext_vector_type(4)));
typedef _Float16 half2v __attribute__((ext_vector_type(2)));
typedef float f32x4 __attribute__((ext_vector_type(4)));

__device__ inline f32x4 MFMA(half8v a, half8v b, f32x4 c) {
    return __builtin_amdgcn_mfma_f32_16x16x32_f16(a, b, c, 0, 0, 0);
}

// ---------------- setup: f16 converts (x, out_w, in_w, rootT/relT) + hist ----
__device__ inline void cvt4(const float* __restrict__ s, _Float16* __restrict__ d, int i) {
    float4 v = ((const float4*)s)[i];
    half4v h;
    h[0] = (_Float16)v.x; h[1] = (_Float16)v.y;
    h[2] = (_Float16)v.z; h[3] = (_Float16)v.w;
    *(half4v*)(d + (size_t)i * 4) = h;
}

__global__ __launch_bounds__(256) void cvt16_kernel(
    const float* __restrict__ x_s, const float* __restrict__ x_t,
    const float* __restrict__ out_w, const float* __restrict__ in_w,
    const float* __restrict__ root_w, const float* __restrict__ rel_w,
    const int* __restrict__ dst_s, const int* __restrict__ dst_t,
    _Float16* __restrict__ x16, _Float16* __restrict__ outw16,
    _Float16* __restrict__ in16, _Float16* __restrict__ bt16,
    int* __restrict__ cnt)
{
    int gid = blockIdx.x * 256 + threadIdx.x, gs = gridDim.x * 256;
    const int nx = N_NODES * DIM / 4;
    const int nw = NLAYER * DIM * DIM / 4;
    const int ni = NLAYER * QDIM * DIM / 4;
    for (int i = gid; i < nx; i += gs) cvt4(x_s, x16, i);
    for (int i = gid; i < nx; i += gs) cvt4(x_t, x16 + N_NODES * DIM, i);
    for (int i = gid; i < nw; i += gs) cvt4(out_w, outw16, i);
    for (int i = gid; i < ni; i += gs) cvt4(in_w, in16, i);
    // transposed f16: bt16[L][m][k][j] = {root,rel}_w[L][j][k]
    const int nb = NLAYER * 2 * DIM * DIM;
    for (int i = gid; i < nb; i += gs) {
        int j = i & 127, k = (i >> 7) & 127, m = (i >> 14) & 1, L = i >> 15;
        const float* B = (m ? rel_w : root_w) + (size_t)L * DIM * DIM;
        bt16[i] = (_Float16)B[j * DIM + k];
    }
    for (int i = gid; i < 2 * NEDGE; i += gs) {
        int side = i >> 16, e = i & (NEDGE - 1);
        const int* dd = side ? dst_t : dst_s;
        atomicAdd(&cnt[side * N_NODES + dd[e]], 1);
    }
}

// ---------------- setup: exclusive scan (2 blocks) ----------------
__global__ __launch_bounds__(256) void scan_kernel(
    const int* __restrict__ cnt, int* __restrict__ row_start, int* __restrict__ cursor)
{
    int side = blockIdx.x;
    int t = threadIdx.x;
    __shared__ int part[256];
    int local[16];
    int s = 0;
    #pragma unroll
    for (int j = 0; j < 16; ++j) { local[j] = cnt[side * N_NODES + t * 16 + j]; s += local[j]; }
    part[t] = s;
    __syncthreads();
    for (int off = 1; off < 256; off <<= 1) {
        int v = (t >= off) ? part[t - off] : 0;
        __syncthreads();
        part[t] += v;
        __syncthreads();
    }
    int run = (t == 0) ? 0 : part[t - 1];
    #pragma unroll
    for (int j = 0; j < 16; ++j) {
        int idx = t * 16 + j;
        row_start[side * (N_NODES + 1) + idx] = run;
        cursor[side * N_NODES + idx] = run;
        run += local[j];
    }
    if (t == 255) row_start[side * (N_NODES + 1) + N_NODES] = run;
}

// ---------------- setup: fused reorder + gather (f16 sorted edge rows) --------
__global__ __launch_bounds__(256) void rg_kernel(
    const int* __restrict__ src_s, const int* __restrict__ dst_s,
    const int* __restrict__ src_t, const int* __restrict__ dst_t,
    const float* __restrict__ ea_s, const float* __restrict__ ea_t,
    int* __restrict__ cursor, int* __restrict__ srcs, _Float16* __restrict__ ea16s)
{
    int t = threadIdx.x;
    int g16 = t >> 4, sub = t & 15, lane = t & 63;
    int ef = blockIdx.x * 16 + g16;                  // [0, 2*NEDGE)
    int side = ef >> 16, e = ef & (NEDGE - 1);
    const int* dd = side ? dst_t : dst_s;
    const int* ss = side ? src_t : src_s;
    const float* ea = side ? ea_t : ea_s;
    int pos = 0;
    if (sub == 0) pos = atomicAdd(&cursor[side * N_NODES + dd[e]], 1);
    pos = __shfl(pos, lane & ~15);                   // broadcast within 16-group
    if (sub == 0) srcs[side * NEDGE + pos] = ss[e];
    const float* sp = ea + (size_t)e * DIM + sub * 8;
    float4 v0 = *(const float4*)(sp);
    float4 v1 = *(const float4*)(sp + 4);
    half8v h;
    h[0]=(_Float16)v0.x; h[1]=(_Float16)v0.y; h[2]=(_Float16)v0.z; h[3]=(_Float16)v0.w;
    h[4]=(_Float16)v1.x; h[5]=(_Float16)v1.y; h[6]=(_Float16)v1.z; h[7]=(_Float16)v1.w;
    *(half8v*)(ea16s + (size_t)(side * NEDGE + pos) * DIM + sub * 8) = h;
}

// ---------------- setup: MFMA weight fold ----------------
// wq16[L][m][i][k] = sum_j in16[L][i][j] * bt16[L][m][k][j]
__global__ __launch_bounds__(256) void wfold_mfma(
    const _Float16* __restrict__ in16, const _Float16* __restrict__ bt16,
    _Float16* __restrict__ wq16)
{
    int lm = blockIdx.z;
    const _Float16* A = in16 + (size_t)(lm >> 1) * QDIM * DIM;
    const _Float16* B = bt16 + (size_t)lm * DIM * DIM;
    _Float16* C = wq16 + (size_t)lm * QDIM * DIM;
    int tid = threadIdx.x;
    int wave = tid >> 6, lane = tid & 63;
    int wm = wave >> 1, wn = wave & 1;
    int row0 = blockIdx.x * 64 + wm * 32;
    int col0 = blockIdx.y * 64 + wn * 32;
    int lr = lane & 15;
    int lk = (lane >> 4) * 8;
    f32x4 zero = {0.f, 0.f, 0.f, 0.f};
    f32x4 acc[2][2] = {{zero, zero}, {zero, zero}};
    const _Float16* Ap0 = A + (size_t)(row0 + lr) * DIM + lk;
    const _Float16* Ap1 = A + (size_t)(row0 + 16 + lr) * DIM + lk;
    const _Float16* Bp0 = B + (size_t)(col0 + lr) * DIM + lk;
    const _Float16* Bp1 = B + (size_t)(col0 + 16 + lr) * DIM + lk;
    #pragma unroll
    for (int k0 = 0; k0 < DIM; k0 += 32) {
        half8v a0 = *(const half8v*)(Ap0 + k0);
        half8v a1 = *(const half8v*)(Ap1 + k0);
        half8v b0 = *(const half8v*)(Bp0 + k0);
        half8v b1 = *(const half8v*)(Bp1 + k0);
        acc[0][0] = MFMA(a0, b0, acc[0][0]);
        acc[0][1] = MFMA(a0, b1, acc[0][1]);
        acc[1][0] = MFMA(a1, b0, acc[1][0]);
        acc[1][1] = MFMA(a1, b1, acc[1][1]);
    }
    int g4 = (lane >> 4) * 4;
    #pragma unroll
    for (int fc = 0; fc < 2; ++fc) {
        int col = col0 + fc * 16 + lr;
        #pragma unroll
        for (int fr = 0; fr < 2; ++fr) {
            int rbase = row0 + fr * 16 + g4;
            #pragma unroll
            for (int j = 0; j < 4; ++j)
                C[(size_t)(rbase + j) * DIM + col] = (_Float16)acc[fr][fc][j];
        }
    }
}

// ---------------- setup: beff[L][384] = Win@brel + bin (f32) ----------------
__global__ __launch_bounds__(256) void beff_kernel(
    const float* __restrict__ in_w, const float* __restrict__ in_b,
    const float* __restrict__ rel_b, float* __restrict__ beff)
{
    int gid = blockIdx.x * 256 + threadIdx.x;
    if (gid >= NLAYER * QDIM) return;
    int L = gid / QDIM, i = gid % QDIM;
    const float* Win = in_w + (size_t)L * QDIM * DIM;
    const float* br = rel_b + (size_t)L * DIM;
    float s = in_b[(size_t)L * QDIM + i];
    #pragma unroll 4
    for (int j = 0; j < DIM; ++j) s += Win[(size_t)i * DIM + j] * br[j];
    beff[gid] = s;
}

// ---------------- per-layer: CSR mean aggregate (quarter-wave, 4-wave blocks) -
__global__ __launch_bounds__(256) void agg_kernel(
    const int* __restrict__ srcs, const _Float16* __restrict__ ea16s,
    const int* __restrict__ row_start,
    const _Float16* __restrict__ x16, _Float16* __restrict__ agg16)
{
    int t = threadIdx.x;
    int wid = t >> 6, lane = t & 63;
    int sub = lane & 15, qe = lane >> 4;
    int wg = blockIdx.x * 4 + wid;            // global wave id, 2048 waves
    for (int node = wg; node < NROWS; node += 2048) {
        int side = node >> 12, n = node & (N_NODES - 1);
        const int* sp = srcs + side * NEDGE;
        const _Float16* ep = ea16s + (size_t)side * NEDGE * DIM + sub * 8;
        const _Float16* xp = x16 + (size_t)side * N_NODES * DIM + sub * 8;
        int rs = row_start[side * (N_NODES + 1) + n];
        int re = row_start[side * (N_NODES + 1) + n + 1];
        float acc[8] = {};
        for (int i = rs + qe; i < re; i += 4) {
            int s = sp[i];
            half8v w = *(const half8v*)(ep + (size_t)i * DIM);
            half8v xv = *(const half8v*)(xp + (size_t)s * DIM);
            #pragma unroll
            for (int j = 0; j < 8; ++j) acc[j] += (float)w[j] * (float)xv[j];
        }
        #pragma unroll
        for (int j = 0; j < 8; ++j) {
            acc[j] += __shfl_xor(acc[j], 16);
            acc[j] += __shfl_xor(acc[j], 32);
        }
        if (qe == 0) {
            float sc = 1.0f / (float)max(re - rs, 1);
            half8v o;
            #pragma unroll
            for (int j = 0; j < 8; ++j) o[j] = (_Float16)(acc[j] * sc);
            *(half8v*)(agg16 + (size_t)node * DIM + sub * 8) = o;
        }
    }
}

// ---------------- per-layer: fused conv+qkv dual-source MFMA GEMM ----------
__global__ __launch_bounds__(256) void qkv2_mfma(
    const _Float16* __restrict__ x16, const _Float16* __restrict__ agg16,
    const _Float16* __restrict__ wq,     // [2][384][128] this layer
    const float* __restrict__ beff,      // [384]
    _Float16* __restrict__ qb16)
{
    int tid = threadIdx.x;
    int wave = tid >> 6, lane = tid & 63;
    int wm = wave >> 1, wn = wave & 1;
    int row0 = blockIdx.x * 64 + wm * 32;
    int col0 = blockIdx.y * 64 + wn * 32;
    int lr = lane & 15;
    int lk = (lane >> 4) * 8;
    f32x4 zero = {0.f, 0.f, 0.f, 0.f};
    f32x4 acc[2][2] = {{zero, zero}, {zero, zero}};
    #pragma unroll
    for (int s = 0; s < 2; ++s) {
        const _Float16* A = s ? agg16 : x16;
        const _Float16* W = wq + (size_t)s * QDIM * DIM;
        const _Float16* Ap0 = A + (size_t)(row0 + lr) * DIM + lk;
        const _Float16* Ap1 = A + (size_t)(row0 + 16 + lr) * DIM + lk;
        const _Float16* Wp0 = W + (size_t)(col0 + lr) * DIM + lk;
        const _Float16* Wp1 = W + (size_t)(col0 + 16 + lr) * DIM + lk;
        #pragma unroll
        for (int k0 = 0; k0 < DIM; k0 += 32) {
            half8v a0 = *(const half8v*)(Ap0 + k0);
            half8v a1 = *(const half8v*)(Ap1 + k0);
            half8v b0 = *(const half8v*)(Wp0 + k0);
            half8v b1 = *(const half8v*)(Wp1 + k0);
            acc[0][0] = MFMA(a0, b0, acc[0][0]);
            acc[0][1] = MFMA(a0, b1, acc[0][1]);
            acc[1][0] = MFMA(a1, b0, acc[1][0]);
            acc[1][1] = MFMA(a1, b1, acc[1][1]);
        }
    }
    int g4 = (lane >> 4) * 4;
    #pragma unroll
    for (int fc = 0; fc < 2; ++fc) {
        int col = col0 + fc * 16 + lr;
        float bv = beff[col];
        #pragma unroll
        for (int fr = 0; fr < 2; ++fr) {
            int rbase = row0 + fr * 16 + g4;
            #pragma unroll
            for (int j = 0; j < 4; ++j) {
                float v = acc[fr][fc][j] + bv;
                qb16[(size_t)(rbase + j) * QDIM + col] = (_Float16)v;
            }
        }
    }
}

// ---------------- per-layer: fused attention + out-proj + LayerNorm ----------
__global__ __launch_bounds__(256) void attn_oln_kernel(
    const _Float16* __restrict__ qkv, const _Float16* __restrict__ outw,
    const float* __restrict__ bias, const float* __restrict__ gamma,
    const float* __restrict__ beta, _Float16* __restrict__ x16out)
{
    int g = blockIdx.x, dir = blockIdx.y, rb = blockIdx.z;
    int qoff  = dir ? N_NODES : 0;
    int kvoff = dir ? 0 : N_NODES;
    int t = threadIdx.x;
    int w = t >> 6, lane = t & 63;         // wave w = head w
    int lr = lane & 15, g4 = lane >> 4;
    __shared__ _Float16 VT[NHEAD][32][136];   // V^T per head: [dim][key]
    __shared__ _Float16 P[NHEAD][16][136];    // normalized P per head (phase2: OL aliases P[0])
    __shared__ float red_s[16][5], red_q[16][5];
    f32x4 zero = {0.f, 0.f, 0.f, 0.f};
    // ---- stage V^T for head w (wave-private) ----
    for (int kk = lane; kk < 128; kk += 64) {
        const _Float16* vp = qkv + (size_t)(kvoff + g * 128 + kk) * QDIM + 2 * DIM + w * DHEAD;
        half8v v0 = *(const half8v*)(vp);
        half8v v1 = *(const half8v*)(vp + 8);
        half8v v2 = *(const half8v*)(vp + 16);
        half8v v3 = *(const half8v*)(vp + 24);
        #pragma unroll
        for (int j = 0; j < 8; ++j) {
            VT[w][j][kk]      = v0[j];
            VT[w][8 + j][kk]  = v1[j];
            VT[w][16 + j][kk] = v2[j];
            VT[w][24 + j][kk] = v3[j];
        }
    }
    // ---- QK^T from global fragments ----
    int qrow0 = qoff + g * 128 + rb * 16;
    const _Float16* qp = qkv + (size_t)(qrow0 + lr) * QDIM + w * DHEAD + g4 * 8;
    half8v qfrag = *(const half8v*)qp;
    f32x4 S[8];
    #pragma unroll
    for (int kf = 0; kf < 8; ++kf) {
        const _Float16* kp = qkv + (size_t)(kvoff + g * 128 + kf * 16 + lr) * QDIM
                             + DIM + w * DHEAD + g4 * 8;
        S[kf] = MFMA(qfrag, *(const half8v*)kp, zero);
    }
    // ---- wave-local softmax; normalized P -> LDS ----
    const float scale = 0.17677669529663687f;  // 1/sqrt(32)
    #pragma unroll
    for (int j = 0; j < 4; ++j) {
        float m = -INFINITY;
        #pragma unroll
        for (int kf = 0; kf < 8; ++kf) m = fmaxf(m, S[kf][j]);
        m *= scale;
        #pragma unroll
        for (int mk = 1; mk < 16; mk <<= 1) m = fmaxf(m, __shfl_xor(m, mk));
        float pj[8];
        float l = 0.f;
        #pragma unroll
        for (int kf = 0; kf < 8; ++kf) {
            float pv = __expf(S[kf][j] * scale - m);
            pj[kf] = pv; l += pv;
        }
        #pragma unroll
        for (int mk = 1; mk < 16; mk <<= 1) l += __shfl_xor(l, mk);
        float linv = 1.0f / l;
        int row = g4 * 4 + j;
        #pragma unroll
        for (int kf = 0; kf < 8; ++kf)
            P[w][row][kf * 16 + lr] = (_Float16)(pj[kf] * linv);
    }
    // ---- PV (wave-private LDS) ----
    f32x4 O[2] = {zero, zero};
    #pragma unroll
    for (int ks = 0; ks < 4; ++ks) {
        half8v pa = *(const half8v*)&P[w][lr][ks * 32 + g4 * 8];
        #pragma unroll
        for (int df = 0; df < 2; ++df) {
            half8v vb = *(const half8v*)&VT[w][df * 16 + lr][ks * 32 + g4 * 8];
            O[df] = MFMA(pa, vb, O[df]);
        }
    }
    __syncthreads();                            // all waves done with P before alias
    // ---- O -> LDS (OL aliases P[0]) ----
    _Float16 (*OL)[136] = P[0];
    #pragma unroll
    for (int df = 0; df < 2; ++df)
        #pragma unroll
        for (int j = 0; j < 4; ++j)
            OL[g4 * 4 + j][w * DHEAD + df * 16 + lr] = (_Float16)O[df][j];
    __syncthreads();
    // ---- out-proj: wave w computes cols [w*32, w*32+32) for all 16 rows ----
    f32x4 acc2[2] = {zero, zero};
    #pragma unroll
    for (int kk = 0; kk < 4; ++kk) {
        half8v a = *(const half8v*)&OL[lr][kk * 32 + g4 * 8];
        #pragma unroll
        for (int ct = 0; ct < 2; ++ct) {
            const _Float16* wp = outw + (size_t)(w * 32 + ct * 16 + lr) * DIM + kk * 32 + g4 * 8;
            acc2[ct] = MFMA(a, *(const half8v*)wp, acc2[ct]);
        }
    }
    // ---- bias + LayerNorm ----
    float v[2][4];
    #pragma unroll
    for (int ct = 0; ct < 2; ++ct) {
        float bv = bias[w * 32 + ct * 16 + lr];
        #pragma unroll
        for (int j = 0; j < 4; ++j) v[ct][j] = acc2[ct][j] + bv;
    }
    #pragma unroll
    for (int j = 0; j < 4; ++j) {
        float ss = v[0][j] + v[1][j];
        float qq = v[0][j] * v[0][j] + v[1][j] * v[1][j];
        #pragma unroll
        for (int mk = 1; mk < 16; mk <<= 1) {
            ss += __shfl_xor(ss, mk);
            qq += __shfl_xor(qq, mk);
        }
        if (lr == 0) {
            red_s[g4 * 4 + j][w] = ss;
            red_q[g4 * 4 + j][w] = qq;
        }
    }
    __syncthreads();
    #pragma unroll
    for (int j = 0; j < 4; ++j) {
        int row = g4 * 4 + j;
        float Sv = red_s[row][0] + red_s[row][1] + red_s[row][2] + red_s[row][3];
        float Qv = red_q[row][0] + red_q[row][1] + red_q[row][2] + red_q[row][3];
        float mu = Sv * (1.0f / 128.0f);
        float inv = rsqrtf(Qv * (1.0f / 128.0f) - mu * mu + 1e-5f);
        #pragma unroll
        for (int ct = 0; ct < 2; ++ct) {
            int col = w * 32 + ct * 16 + lr;
            float o = (v[ct][j] - mu) * inv * gamma[col] + beta[col];
            x16out[(size_t)(qrow0 + row) * DIM + col] = (_Float16)o;
        }
    }
}

// ---------------- pool + cosine ----------------
__global__ __launch_bounds__(256) void poolcos_kernel(
    const _Float16* __restrict__ x16, const float* __restrict__ gw,
    const float* __restrict__ gb, float* __restrict__ out)
{
    int g = blockIdx.x, t = threadIdx.x;
    int side = t >> 7, r = t & 127;
    __shared__ float sm[2][128];
    __shared__ float al[2][128];
    __shared__ float pl[2][DIM];
    const _Float16* xr = x16 + (size_t)(side * N_NODES + g * 128 + r) * DIM;
    float dot = gb[0];
    #pragma unroll
    for (int d = 0; d < DIM; d += 8) {
        half8v xv = *(const half8v*)(xr + d);
        #pragma unroll
        for (int u = 0; u < 8; ++u) dot += (float)xv[u] * gw[d + u];
    }
    float gate = 1.0f / (1.0f + __expf(-dot));
    sm[side][r] = gate; __syncthreads();
    for (int sN = 64; sN > 0; sN >>= 1) {
        if (r < sN) sm[side][r] = fmaxf(sm[side][r], sm[side][r + sN]);
        __syncthreads();
    }
    float m = sm[side][0]; __syncthreads();
    float e = __expf(gate - m);
    sm[side][r] = e; __syncthreads();
    for (int sN = 64; sN > 0; sN >>= 1) {
        if (r < sN) sm[side][r] += sm[side][r + sN];
        __syncthreads();
    }
    al[side][r] = e / sm[side][0];
    __syncthreads();
    int d = t & 127;
    float acc = 0.0f;
    const _Float16* xg = x16 + (size_t)(side * N_NODES + g * 128) * DIM;
    for (int n = 0; n < 128; ++n) acc += al[side][n] * (float)xg[(size_t)n * DIM + d];
    pl[side][d] = acc;
    __syncthreads();
    if (t < 64) {
        float a0 = pl[0][t], a1 = pl[0][64 + t];
        float b0 = pl[1][t], b1 = pl[1][64 + t];
        float saa = a0 * a0 + a1 * a1;
        float sbb = b0 * b0 + b1 * b1;
        float sab = a0 * b0 + a1 * b1;
        #pragma unroll
        for (int off = 32; off; off >>= 1) {
            saa += __shfl_down(saa, off);
            sbb += __shfl_down(sbb, off);
            sab += __shfl_down(sab, off);
        }
        if (t == 0) {
            float na = fmaxf(sqrtf(saa), 1e-12f);
            float nb = fmaxf(sqrtf(sbb), 1e-12f);
            out[g] = sab / (na * nb);
        }
    }
}

extern "C" void kernel_launch(void* const* d_in, const int* in_sizes, int n_in,
                              void* d_out, int out_size, void* d_ws, size_t ws_size,
                              hipStream_t stream)
{
    const float* x_s    = (const float*)d_in[0];
    const float* x_t    = (const float*)d_in[1];
    const int*   ei_s   = (const int*)d_in[2];
    const float* ea_s   = (const float*)d_in[3];
    const int*   ei_t   = (const int*)d_in[4];
    const float* ea_t   = (const float*)d_in[5];
    const float* rel_w  = (const float*)d_in[8];
    const float* rel_b  = (const float*)d_in[9];
    const float* root_w = (const float*)d_in[10];
    const float* in_w   = (const float*)d_in[11];
    const float* in_b   = (const float*)d_in[12];
    const float* out_w  = (const float*)d_in[13];
    const float* out_b  = (const float*)d_in[14];
    const float* g_ln   = (const float*)d_in[15];
    const float* b_ln   = (const float*)d_in[16];
    const float* gate_w = (const float*)d_in[17];
    const float* gate_b = (const float*)d_in[18];
    float* out = (float*)d_out;

    const size_t RD = (size_t)NROWS * DIM;
    _Float16* h16p = (_Float16*)d_ws;
    _Float16* x16    = h16p; h16p += RD;
    _Float16* agg16  = h16p; h16p += RD;
    _Float16* qb16   = h16p; h16p += RD * 3;
    _Float16* ea16s  = h16p; h16p += (size_t)2 * NEDGE * DIM;
    _Float16* outw16 = h16p; h16p += (size_t)NLAYER * DIM * DIM;
    _Float16* wq16   = h16p; h16p += (size_t)NLAYER * 2 * QDIM * DIM;
    _Float16* in16   = h16p; h16p += (size_t)NLAYER * QDIM * DIM;
    _Float16* bt16   = h16p; h16p += (size_t)NLAYER * 2 * DIM * DIM;
    float* fws = (float*)h16p;
    float* beff = fws; fws += NLAYER * QDIM;
    int* iws = (int*)fws;
    int* cnt       = iws; iws += 2 * N_NODES;
    int* cursor    = iws; iws += 2 * N_NODES;
    int* row_start = iws; iws += 2 * (N_NODES + 1);
    int* srcs      = iws; iws += 2 * NEDGE;

    const int* src_s = ei_s, *dst_s = ei_s + NEDGE;
    const int* src_t = ei_t, *dst_t = ei_t + NEDGE;

    // setup
    hipMemsetAsync(cnt, 0, 2 * N_NODES * 4, stream);
    cvt16_kernel<<<512, 256, 0, stream>>>(x_s, x_t, out_w, in_w, root_w, rel_w,
                                          dst_s, dst_t, x16, outw16, in16, bt16, cnt);
    scan_kernel<<<2, 256, 0, stream>>>(cnt, row_start, cursor);
    rg_kernel<<<2 * NEDGE / 16, 256, 0, stream>>>(src_s, dst_s, src_t, dst_t,
                                                  ea_s, ea_t, cursor, srcs, ea16s);
    {
        dim3 gw(QDIM / 64, DIM / 64, NLAYER * 2);   // 6 x 2 x 8
        wfold_mfma<<<gw, 256, 0, stream>>>(in16, bt16, wq16);
    }
    beff_kernel<<<(NLAYER * QDIM + 255) / 256, 256, 0, stream>>>(in_w, in_b, rel_b, beff);

    dim3 gq(NROWS / 64, QDIM / 64);   // 128 x 6
    dim3 gattn(BGRAPH, 2, 8);          // 512 blocks

    for (int i = 0; i < NLAYER; ++i) {
        const _Float16* wq   = wq16   + (size_t)i * 2 * QDIM * DIM;
        const float*    be   = beff   + (size_t)i * QDIM;
        const _Float16* wout = outw16 + (size_t)i * DIM * DIM;
        const float*    bout = out_b  + (size_t)i * DIM;
        const float*    lg   = g_ln   + (size_t)i * DIM;
        const float*    lb   = b_ln   + (size_t)i * DIM;

        agg_kernel<<<512, 256, 0, stream>>>(srcs, ea16s, row_start, x16, agg16);
        qkv2_mfma<<<gq, 256, 0, stream>>>(x16, agg16, wq, be, qb16);
        attn_oln_kernel<<<gattn, 256, 0, stream>>>(qb16, wout, bout, lg, lb, x16);
    }

    poolcos_kernel<<<BGRAPH, 256, 0, stream>>>(x16, gate_w, gate_b, out);
}

// Round 13
// 207.035 us; speedup vs baseline: 1.0956x; 1.0956x over previous
//
#include <hip/hip_runtime.h>
#include <math.h>

#define N_NODES 4096
#define NROWS   8192      // both sides stacked
#define BGRAPH  32
#define NEDGE   65536
#define DIM     128
#define NLAYER  4
#define NHEAD   4
#define DHEAD   32
#define QDIM    384       // 3*DIM

typedef _Float16 half8v __attribute__((ext_vector_type(8)));
typedef _Float16 half4v __attribute__((ext_vector_type(4)));
typedef _Float16 half2v __attribute__((ext_vector_type(2)));
typedef float f32x4 __attribute__((ext_vector_type(4)));

__device__ inline f32x4 MFMA(half8v a, half8v b, f32x4 c) {
    return __builtin_amdgcn_mfma_f32_16x16x32_f16(a, b, c, 0, 0, 0);
}

// ---------------- setup: f16 converts (x, out_w, in_w, rootT/relT) + hist ----
__device__ inline void cvt4(const float* __restrict__ s, _Float16* __restrict__ d, int i) {
    float4 v = ((const float4*)s)[i];
    half4v h;
    h[0] = (_Float16)v.x; h[1] = (_Float16)v.y;
    h[2] = (_Float16)v.z; h[3] = (_Float16)v.w;
    *(half4v*)(d + (size_t)i * 4) = h;
}

__global__ __launch_bounds__(256) void cvt16_kernel(
    const float* __restrict__ x_s, const float* __restrict__ x_t,
    const float* __restrict__ out_w, const float* __restrict__ in_w,
    const float* __restrict__ root_w, const float* __restrict__ rel_w,
    const int* __restrict__ dst_s, const int* __restrict__ dst_t,
    _Float16* __restrict__ x16, _Float16* __restrict__ outw16,
    _Float16* __restrict__ in16, _Float16* __restrict__ bt16,
    int* __restrict__ cnt)
{
    int gid = blockIdx.x * 256 + threadIdx.x, gs = gridDim.x * 256;
    const int nx = N_NODES * DIM / 4;
    const int nw = NLAYER * DIM * DIM / 4;
    const int ni = NLAYER * QDIM * DIM / 4;
    for (int i = gid; i < nx; i += gs) cvt4(x_s, x16, i);
    for (int i = gid; i < nx; i += gs) cvt4(x_t, x16 + N_NODES * DIM, i);
    for (int i = gid; i < nw; i += gs) cvt4(out_w, outw16, i);
    for (int i = gid; i < ni; i += gs) cvt4(in_w, in16, i);
    // transposed f16: bt16[L][m][k][j] = {root,rel}_w[L][j][k]
    const int nb = NLAYER * 2 * DIM * DIM;
    for (int i = gid; i < nb; i += gs) {
        int j = i & 127, k = (i >> 7) & 127, m = (i >> 14) & 1, L = i >> 15;
        const float* B = (m ? rel_w : root_w) + (size_t)L * DIM * DIM;
        bt16[i] = (_Float16)B[j * DIM + k];
    }
    for (int i = gid; i < 2 * NEDGE; i += gs) {
        int side = i >> 16, e = i & (NEDGE - 1);
        const int* dd = side ? dst_t : dst_s;
        atomicAdd(&cnt[side * N_NODES + dd[e]], 1);
    }
}

// ---------------- setup: exclusive scan (2 blocks) ----------------
__global__ __launch_bounds__(256) void scan_kernel(
    const int* __restrict__ cnt, int* __restrict__ row_start, int* __restrict__ cursor)
{
    int side = blockIdx.x;
    int t = threadIdx.x;
    __shared__ int part[256];
    int local[16];
    int s = 0;
    #pragma unroll
    for (int j = 0; j < 16; ++j) { local[j] = cnt[side * N_NODES + t * 16 + j]; s += local[j]; }
    part[t] = s;
    __syncthreads();
    for (int off = 1; off < 256; off <<= 1) {
        int v = (t >= off) ? part[t - off] : 0;
        __syncthreads();
        part[t] += v;
        __syncthreads();
    }
    int run = (t == 0) ? 0 : part[t - 1];
    #pragma unroll
    for (int j = 0; j < 16; ++j) {
        int idx = t * 16 + j;
        row_start[side * (N_NODES + 1) + idx] = run;
        cursor[side * N_NODES + idx] = run;
        run += local[j];
    }
    if (t == 255) row_start[side * (N_NODES + 1) + N_NODES] = run;
}

// ---------------- setup: fused reorder + gather (f16 sorted edge rows) --------
__global__ __launch_bounds__(256) void rg_kernel(
    const int* __restrict__ src_s, const int* __restrict__ dst_s,
    const int* __restrict__ src_t, const int* __restrict__ dst_t,
    const float* __restrict__ ea_s, const float* __restrict__ ea_t,
    int* __restrict__ cursor, int* __restrict__ srcs, _Float16* __restrict__ ea16s)
{
    int t = threadIdx.x;
    int g16 = t >> 4, sub = t & 15, lane = t & 63;
    int ef = blockIdx.x * 16 + g16;                  // [0, 2*NEDGE)
    int side = ef >> 16, e = ef & (NEDGE - 1);
    const int* dd = side ? dst_t : dst_s;
    const int* ss = side ? src_t : src_s;
    const float* ea = side ? ea_t : ea_s;
    int pos = 0;
    if (sub == 0) pos = atomicAdd(&cursor[side * N_NODES + dd[e]], 1);
    pos = __shfl(pos, lane & ~15);                   // broadcast within 16-group
    if (sub == 0) srcs[side * NEDGE + pos] = ss[e];
    const float* sp = ea + (size_t)e * DIM + sub * 8;
    float4 v0 = *(const float4*)(sp);
    float4 v1 = *(const float4*)(sp + 4);
    half8v h;
    h[0]=(_Float16)v0.x; h[1]=(_Float16)v0.y; h[2]=(_Float16)v0.z; h[3]=(_Float16)v0.w;
    h[4]=(_Float16)v1.x; h[5]=(_Float16)v1.y; h[6]=(_Float16)v1.z; h[7]=(_Float16)v1.w;
    *(half8v*)(ea16s + (size_t)(side * NEDGE + pos) * DIM + sub * 8) = h;
}

// ---------------- setup: MFMA weight fold ----------------
// wq16[L][m][i][k] = sum_j in16[L][i][j] * bt16[L][m][k][j]
__global__ __launch_bounds__(256) void wfold_mfma(
    const _Float16* __restrict__ in16, const _Float16* __restrict__ bt16,
    _Float16* __restrict__ wq16)
{
    int lm = blockIdx.z;
    const _Float16* A = in16 + (size_t)(lm >> 1) * QDIM * DIM;
    const _Float16* B = bt16 + (size_t)lm * DIM * DIM;
    _Float16* C = wq16 + (size_t)lm * QDIM * DIM;
    int tid = threadIdx.x;
    int wave = tid >> 6, lane = tid & 63;
    int wm = wave >> 1, wn = wave & 1;
    int row0 = blockIdx.x * 64 + wm * 32;
    int col0 = blockIdx.y * 64 + wn * 32;
    int lr = lane & 15;
    int lk = (lane >> 4) * 8;
    f32x4 zero = {0.f, 0.f, 0.f, 0.f};
    f32x4 acc[2][2] = {{zero, zero}, {zero, zero}};
    const _Float16* Ap0 = A + (size_t)(row0 + lr) * DIM + lk;
    const _Float16* Ap1 = A + (size_t)(row0 + 16 + lr) * DIM + lk;
    const _Float16* Bp0 = B + (size_t)(col0 + lr) * DIM + lk;
    const _Float16* Bp1 = B + (size_t)(col0 + 16 + lr) * DIM + lk;
    #pragma unroll
    for (int k0 = 0; k0 < DIM; k0 += 32) {
        half8v a0 = *(const half8v*)(Ap0 + k0);
        half8v a1 = *(const half8v*)(Ap1 + k0);
        half8v b0 = *(const half8v*)(Bp0 + k0);
        half8v b1 = *(const half8v*)(Bp1 + k0);
        acc[0][0] = MFMA(a0, b0, acc[0][0]);
        acc[0][1] = MFMA(a0, b1, acc[0][1]);
        acc[1][0] = MFMA(a1, b0, acc[1][0]);
        acc[1][1] = MFMA(a1, b1, acc[1][1]);
    }
    int g4 = (lane >> 4) * 4;
    #pragma unroll
    for (int fc = 0; fc < 2; ++fc) {
        int col = col0 + fc * 16 + lr;
        #pragma unroll
        for (int fr = 0; fr < 2; ++fr) {
            int rbase = row0 + fr * 16 + g4;
            #pragma unroll
            for (int j = 0; j < 4; ++j)
                C[(size_t)(rbase + j) * DIM + col] = (_Float16)acc[fr][fc][j];
        }
    }
}

// ---------------- setup: beff[L][384] = Win@brel + bin (f32) ----------------
__global__ __launch_bounds__(256) void beff_kernel(
    const float* __restrict__ in_w, const float* __restrict__ in_b,
    const float* __restrict__ rel_b, float* __restrict__ beff)
{
    int gid = blockIdx.x * 256 + threadIdx.x;
    if (gid >= NLAYER * QDIM) return;
    int L = gid / QDIM, i = gid % QDIM;
    const float* Win = in_w + (size_t)L * QDIM * DIM;
    const float* br = rel_b + (size_t)L * DIM;
    float s = in_b[(size_t)L * QDIM + i];
    #pragma unroll 4
    for (int j = 0; j < DIM; ++j) s += Win[(size_t)i * DIM + j] * br[j];
    beff[gid] = s;
}

// ---------------- per-layer: CSR mean aggregate (1 wave per node, r11) -------
__global__ __launch_bounds__(64) void agg_kernel(
    const int* __restrict__ srcs, const _Float16* __restrict__ ea16s,
    const int* __restrict__ row_start,
    const _Float16* __restrict__ x16, _Float16* __restrict__ agg16)
{
    int n = blockIdx.x, side = blockIdx.y;
    int lane = threadIdx.x;
    const int* sp = srcs + side * NEDGE;
    const _Float16* ep = ea16s + (size_t)side * NEDGE * DIM + lane * 2;
    const _Float16* xp = x16 + (size_t)side * N_NODES * DIM + lane * 2;
    int rs = row_start[side * (N_NODES + 1) + n];
    int re = row_start[side * (N_NODES + 1) + n + 1];
    float ax = 0.f, ay = 0.f;
    int i = rs;
    for (; i + 2 <= re; i += 2) {
        int s0 = sp[i], s1 = sp[i + 1];
        half2v w0 = *(const half2v*)(ep + (size_t)i * DIM);
        half2v w1 = *(const half2v*)(ep + (size_t)(i + 1) * DIM);
        half2v x0 = *(const half2v*)(xp + (size_t)s0 * DIM);
        half2v x1 = *(const half2v*)(xp + (size_t)s1 * DIM);
        ax += (float)w0[0] * (float)x0[0] + (float)w1[0] * (float)x1[0];
        ay += (float)w0[1] * (float)x0[1] + (float)w1[1] * (float)x1[1];
    }
    if (i < re) {
        int s0 = sp[i];
        half2v w0 = *(const half2v*)(ep + (size_t)i * DIM);
        half2v x0 = *(const half2v*)(xp + (size_t)s0 * DIM);
        ax += (float)w0[0] * (float)x0[0];
        ay += (float)w0[1] * (float)x0[1];
    }
    float sc = 1.0f / (float)max(re - rs, 1);
    half2v o; o[0] = (_Float16)(ax * sc); o[1] = (_Float16)(ay * sc);
    *(half2v*)(agg16 + (size_t)(side * N_NODES + n) * DIM + lane * 2) = o;
}

// ---------------- per-layer: fused conv+qkv dual-source MFMA GEMM ----------
__global__ __launch_bounds__(256) void qkv2_mfma(
    const _Float16* __restrict__ x16, const _Float16* __restrict__ agg16,
    const _Float16* __restrict__ wq,     // [2][384][128] this layer
    const float* __restrict__ beff,      // [384]
    _Float16* __restrict__ qb16)
{
    int tid = threadIdx.x;
    int wave = tid >> 6, lane = tid & 63;
    int wm = wave >> 1, wn = wave & 1;
    int row0 = blockIdx.x * 64 + wm * 32;
    int col0 = blockIdx.y * 64 + wn * 32;
    int lr = lane & 15;
    int lk = (lane >> 4) * 8;
    f32x4 zero = {0.f, 0.f, 0.f, 0.f};
    f32x4 acc[2][2] = {{zero, zero}, {zero, zero}};
    #pragma unroll
    for (int s = 0; s < 2; ++s) {
        const _Float16* A = s ? agg16 : x16;
        const _Float16* W = wq + (size_t)s * QDIM * DIM;
        const _Float16* Ap0 = A + (size_t)(row0 + lr) * DIM + lk;
        const _Float16* Ap1 = A + (size_t)(row0 + 16 + lr) * DIM + lk;
        const _Float16* Wp0 = W + (size_t)(col0 + lr) * DIM + lk;
        const _Float16* Wp1 = W + (size_t)(col0 + 16 + lr) * DIM + lk;
        #pragma unroll
        for (int k0 = 0; k0 < DIM; k0 += 32) {
            half8v a0 = *(const half8v*)(Ap0 + k0);
            half8v a1 = *(const half8v*)(Ap1 + k0);
            half8v b0 = *(const half8v*)(Wp0 + k0);
            half8v b1 = *(const half8v*)(Wp1 + k0);
            acc[0][0] = MFMA(a0, b0, acc[0][0]);
            acc[0][1] = MFMA(a0, b1, acc[0][1]);
            acc[1][0] = MFMA(a1, b0, acc[1][0]);
            acc[1][1] = MFMA(a1, b1, acc[1][1]);
        }
    }
    int g4 = (lane >> 4) * 4;
    #pragma unroll
    for (int fc = 0; fc < 2; ++fc) {
        int col = col0 + fc * 16 + lr;
        float bv = beff[col];
        #pragma unroll
        for (int fr = 0; fr < 2; ++fr) {
            int rbase = row0 + fr * 16 + g4;
            #pragma unroll
            for (int j = 0; j < 4; ++j) {
                float v = acc[fr][fc][j] + bv;
                qb16[(size_t)(rbase + j) * QDIM + col] = (_Float16)v;
            }
        }
    }
}

// ---------------- per-layer: fused attention + out-proj + LayerNorm ----------
__global__ __launch_bounds__(256) void attn_oln_kernel(
    const _Float16* __restrict__ qkv, const _Float16* __restrict__ outw,
    const float* __restrict__ bias, const float* __restrict__ gamma,
    const float* __restrict__ beta, _Float16* __restrict__ x16out)
{
    int g = blockIdx.x, dir = blockIdx.y, rb = blockIdx.z;
    int qoff  = dir ? N_NODES : 0;
    int kvoff = dir ? 0 : N_NODES;
    int t = threadIdx.x;
    int w = t >> 6, lane = t & 63;         // wave w = head w
    int lr = lane & 15, g4 = lane >> 4;
    __shared__ _Float16 VT[NHEAD][32][136];   // V^T per head: [dim][key]
    __shared__ _Float16 P[NHEAD][16][136];    // normalized P per head (phase2: OL aliases P[0])
    __shared__ float red_s[16][5], red_q[16][5];
    f32x4 zero = {0.f, 0.f, 0.f, 0.f};
    // ---- stage V^T for head w (wave-private) ----
    for (int kk = lane; kk < 128; kk += 64) {
        const _Float16* vp = qkv + (size_t)(kvoff + g * 128 + kk) * QDIM + 2 * DIM + w * DHEAD;
        half8v v0 = *(const half8v*)(vp);
        half8v v1 = *(const half8v*)(vp + 8);
        half8v v2 = *(const half8v*)(vp + 16);
        half8v v3 = *(const half8v*)(vp + 24);
        #pragma unroll
        for (int j = 0; j < 8; ++j) {
            VT[w][j][kk]      = v0[j];
            VT[w][8 + j][kk]  = v1[j];
            VT[w][16 + j][kk] = v2[j];
            VT[w][24 + j][kk] = v3[j];
        }
    }
    // ---- QK^T from global fragments ----
    int qrow0 = qoff + g * 128 + rb * 16;
    const _Float16* qp = qkv + (size_t)(qrow0 + lr) * QDIM + w * DHEAD + g4 * 8;
    half8v qfrag = *(const half8v*)qp;
    f32x4 S[8];
    #pragma unroll
    for (int kf = 0; kf < 8; ++kf) {
        const _Float16* kp = qkv + (size_t)(kvoff + g * 128 + kf * 16 + lr) * QDIM
                             + DIM + w * DHEAD + g4 * 8;
        S[kf] = MFMA(qfrag, *(const half8v*)kp, zero);
    }
    // ---- wave-local softmax; normalized P -> LDS ----
    const float scale = 0.17677669529663687f;  // 1/sqrt(32)
    #pragma unroll
    for (int j = 0; j < 4; ++j) {
        float m = -INFINITY;
        #pragma unroll
        for (int kf = 0; kf < 8; ++kf) m = fmaxf(m, S[kf][j]);
        m *= scale;
        #pragma unroll
        for (int mk = 1; mk < 16; mk <<= 1) m = fmaxf(m, __shfl_xor(m, mk));
        float pj[8];
        float l = 0.f;
        #pragma unroll
        for (int kf = 0; kf < 8; ++kf) {
            float pv = __expf(S[kf][j] * scale - m);
            pj[kf] = pv; l += pv;
        }
        #pragma unroll
        for (int mk = 1; mk < 16; mk <<= 1) l += __shfl_xor(l, mk);
        float linv = 1.0f / l;
        int row = g4 * 4 + j;
        #pragma unroll
        for (int kf = 0; kf < 8; ++kf)
            P[w][row][kf * 16 + lr] = (_Float16)(pj[kf] * linv);
    }
    // ---- PV (wave-private LDS) ----
    f32x4 O[2] = {zero, zero};
    #pragma unroll
    for (int ks = 0; ks < 4; ++ks) {
        half8v pa = *(const half8v*)&P[w][lr][ks * 32 + g4 * 8];
        #pragma unroll
        for (int df = 0; df < 2; ++df) {
            half8v vb = *(const half8v*)&VT[w][df * 16 + lr][ks * 32 + g4 * 8];
            O[df] = MFMA(pa, vb, O[df]);
        }
    }
    __syncthreads();                            // all waves done with P before alias
    // ---- O -> LDS (OL aliases P[0]) ----
    _Float16 (*OL)[136] = P[0];
    #pragma unroll
    for (int df = 0; df < 2; ++df)
        #pragma unroll
        for (int j = 0; j < 4; ++j)
            OL[g4 * 4 + j][w * DHEAD + df * 16 + lr] = (_Float16)O[df][j];
    __syncthreads();
    // ---- out-proj: wave w computes cols [w*32, w*32+32) for all 16 rows ----
    f32x4 acc2[2] = {zero, zero};
    #pragma unroll
    for (int kk = 0; kk < 4; ++kk) {
        half8v a = *(const half8v*)&OL[lr][kk * 32 + g4 * 8];
        #pragma unroll
        for (int ct = 0; ct < 2; ++ct) {
            const _Float16* wp = outw + (size_t)(w * 32 + ct * 16 + lr) * DIM + kk * 32 + g4 * 8;
            acc2[ct] = MFMA(a, *(const half8v*)wp, acc2[ct]);
        }
    }
    // ---- bias + LayerNorm ----
    float v[2][4];
    #pragma unroll
    for (int ct = 0; ct < 2; ++ct) {
        float bv = bias[w * 32 + ct * 16 + lr];
        #pragma unroll
        for (int j = 0; j < 4; ++j) v[ct][j] = acc2[ct][j] + bv;
    }
    #pragma unroll
    for (int j = 0; j < 4; ++j) {
        float ss = v[0][j] + v[1][j];
        float qq = v[0][j] * v[0][j] + v[1][j] * v[1][j];
        #pragma unroll
        for (int mk = 1; mk < 16; mk <<= 1) {
            ss += __shfl_xor(ss, mk);
            qq += __shfl_xor(qq, mk);
        }
        if (lr == 0) {
            red_s[g4 * 4 + j][w] = ss;
            red_q[g4 * 4 + j][w] = qq;
        }
    }
    __syncthreads();
    #pragma unroll
    for (int j = 0; j < 4; ++j) {
        int row = g4 * 4 + j;
        float Sv = red_s[row][0] + red_s[row][1] + red_s[row][2] + red_s[row][3];
        float Qv = red_q[row][0] + red_q[row][1] + red_q[row][2] + red_q[row][3];
        float mu = Sv * (1.0f / 128.0f);
        float inv = rsqrtf(Qv * (1.0f / 128.0f) - mu * mu + 1e-5f);
        #pragma unroll
        for (int ct = 0; ct < 2; ++ct) {
            int col = w * 32 + ct * 16 + lr;
            float o = (v[ct][j] - mu) * inv * gamma[col] + beta[col];
            x16out[(size_t)(qrow0 + row) * DIM + col] = (_Float16)o;
        }
    }
}

// ---------------- pool + cosine ----------------
__global__ __launch_bounds__(256) void poolcos_kernel(
    const _Float16* __restrict__ x16, const float* __restrict__ gw,
    const float* __restrict__ gb, float* __restrict__ out)
{
    int g = blockIdx.x, t = threadIdx.x;
    int side = t >> 7, r = t & 127;
    __shared__ float sm[2][128];
    __shared__ float al[2][128];
    __shared__ float pl[2][DIM];
    const _Float16* xr = x16 + (size_t)(side * N_NODES + g * 128 + r) * DIM;
    float dot = gb[0];
    #pragma unroll
    for (int d = 0; d < DIM; d += 8) {
        half8v xv = *(const half8v*)(xr + d);
        #pragma unroll
        for (int u = 0; u < 8; ++u) dot += (float)xv[u] * gw[d + u];
    }
    float gate = 1.0f / (1.0f + __expf(-dot));
    sm[side][r] = gate; __syncthreads();
    for (int sN = 64; sN > 0; sN >>= 1) {
        if (r < sN) sm[side][r] = fmaxf(sm[side][r], sm[side][r + sN]);
        __syncthreads();
    }
    float m = sm[side][0]; __syncthreads();
    float e = __expf(gate - m);
    sm[side][r] = e; __syncthreads();
    for (int sN = 64; sN > 0; sN >>= 1) {
        if (r < sN) sm[side][r] += sm[side][r + sN];
        __syncthreads();
    }
    al[side][r] = e / sm[side][0];
    __syncthreads();
    int d = t & 127;
    float acc = 0.0f;
    const _Float16* xg = x16 + (size_t)(side * N_NODES + g * 128) * DIM;
    for (int n = 0; n < 128; ++n) acc += al[side][n] * (float)xg[(size_t)n * DIM + d];
    pl[side][d] = acc;
    __syncthreads();
    if (t < 64) {
        float a0 = pl[0][t], a1 = pl[0][64 + t];
        float b0 = pl[1][t], b1 = pl[1][64 + t];
        float saa = a0 * a0 + a1 * a1;
        float sbb = b0 * b0 + b1 * b1;
        float sab = a0 * b0 + a1 * b1;
        #pragma unroll
        for (int off = 32; off; off >>= 1) {
            saa += __shfl_down(saa, off);
            sbb += __shfl_down(sbb, off);
            sab += __shfl_down(sab, off);
        }
        if (t == 0) {
            float na = fmaxf(sqrtf(saa), 1e-12f);
            float nb = fmaxf(sqrtf(sbb), 1e-12f);
            out[g] = sab / (na * nb);
        }
    }
}

extern "C" void kernel_launch(void* const* d_in, const int* in_sizes, int n_in,
                              void* d_out, int out_size, void* d_ws, size_t ws_size,
                              hipStream_t stream)
{
    const float* x_s    = (const float*)d_in[0];
    const float* x_t    = (const float*)d_in[1];
    const int*   ei_s   = (const int*)d_in[2];
    const float* ea_s   = (const float*)d_in[3];
    const int*   ei_t   = (const int*)d_in[4];
    const float* ea_t   = (const float*)d_in[5];
    const float* rel_w  = (const float*)d_in[8];
    const float* rel_b  = (const float*)d_in[9];
    const float* root_w = (const float*)d_in[10];
    const float* in_w   = (const float*)d_in[11];
    const float* in_b   = (const float*)d_in[12];
    const float* out_w  = (const float*)d_in[13];
    const float* out_b  = (const float*)d_in[14];
    const float* g_ln   = (const float*)d_in[15];
    const float* b_ln   = (const float*)d_in[16];
    const float* gate_w = (const float*)d_in[17];
    const float* gate_b = (const float*)d_in[18];
    float* out = (float*)d_out;

    const size_t RD = (size_t)NROWS * DIM;
    _Float16* h16p = (_Float16*)d_ws;
    _Float16* x16    = h16p; h16p += RD;
    _Float16* agg16  = h16p; h16p += RD;
    _Float16* qb16   = h16p; h16p += RD * 3;
    _Float16* ea16s  = h16p; h16p += (size_t)2 * NEDGE * DIM;
    _Float16* outw16 = h16p; h16p += (size_t)NLAYER * DIM * DIM;
    _Float16* wq16   = h16p; h16p += (size_t)NLAYER * 2 * QDIM * DIM;
    _Float16* in16   = h16p; h16p += (size_t)NLAYER * QDIM * DIM;
    _Float16* bt16   = h16p; h16p += (size_t)NLAYER * 2 * DIM * DIM;
    float* fws = (float*)h16p;
    float* beff = fws; fws += NLAYER * QDIM;
    int* iws = (int*)fws;
    int* cnt       = iws; iws += 2 * N_NODES;
    int* cursor    = iws; iws += 2 * N_NODES;
    int* row_start = iws; iws += 2 * (N_NODES + 1);
    int* srcs      = iws; iws += 2 * NEDGE;

    const int* src_s = ei_s, *dst_s = ei_s + NEDGE;
    const int* src_t = ei_t, *dst_t = ei_t + NEDGE;

    // setup
    hipMemsetAsync(cnt, 0, 2 * N_NODES * 4, stream);
    cvt16_kernel<<<512, 256, 0, stream>>>(x_s, x_t, out_w, in_w, root_w, rel_w,
                                          dst_s, dst_t, x16, outw16, in16, bt16, cnt);
    scan_kernel<<<2, 256, 0, stream>>>(cnt, row_start, cursor);
    rg_kernel<<<2 * NEDGE / 16, 256, 0, stream>>>(src_s, dst_s, src_t, dst_t,
                                                  ea_s, ea_t, cursor, srcs, ea16s);
    {
        dim3 gw(QDIM / 64, DIM / 64, NLAYER * 2);   // 6 x 2 x 8
        wfold_mfma<<<gw, 256, 0, stream>>>(in16, bt16, wq16);
    }
    beff_kernel<<<(NLAYER * QDIM + 255) / 256, 256, 0, stream>>>(in_w, in_b, rel_b, beff);

    dim3 gq(NROWS / 64, QDIM / 64);   // 128 x 6
    dim3 gagg(N_NODES, 2);
    dim3 gattn(BGRAPH, 2, 8);          // 512 blocks

    for (int i = 0; i < NLAYER; ++i) {
        const _Float16* wq   = wq16   + (size_t)i * 2 * QDIM * DIM;
        const float*    be   = beff   + (size_t)i * QDIM;
        const _Float16* wout = outw16 + (size_t)i * DIM * DIM;
        const float*    bout = out_b  + (size_t)i * DIM;
        const float*    lg   = g_ln   + (size_t)i * DIM;
        const float*    lb   = b_ln   + (size_t)i * DIM;

        agg_kernel<<<gagg, 64, 0, stream>>>(srcs, ea16s, row_start, x16, agg16);
        qkv2_mfma<<<gq, 256, 0, stream>>>(x16, agg16, wq, be, qb16);
        attn_oln_kernel<<<gattn, 256, 0, stream>>>(qb16, wout, bout, lg, lb, x16);
    }

    poolcos_kernel<<<BGRAPH, 256, 0, stream>>>(x16, gate_w, gate_b, out);
}

// Round 14
// 205.328 us; speedup vs baseline: 1.1047x; 1.0083x over previous
//
#include <hip/hip_runtime.h>
#include <math.h>

#define N_NODES 4096
#define NROWS   8192      // both sides stacked
#define BGRAPH  32
#define NEDGE   65536
#define DIM     128
#define NLAYER  4
#define NHEAD   4
#define DHEAD   32
#define QDIM    384       // 3*DIM

typedef _Float16 half8v __attribute__((ext_vector_type(8)));
typedef _Float16 half4v __attribute__((ext_vector_type(4)));
typedef _Float16 half2v __attribute__((ext_vector_type(2)));
typedef float f32x4 __attribute__((ext_vector_type(4)));

__device__ inline f32x4 MFMA(half8v a, half8v b, f32x4 c) {
    return __builtin_amdgcn_mfma_f32_16x16x32_f16(a, b, c, 0, 0, 0);
}

// ---------------- setup: f16 converts (x, out_w, in_w, rootT/relT) + hist ----
__device__ inline void cvt4(const float* __restrict__ s, _Float16* __restrict__ d, int i) {
    float4 v = ((const float4*)s)[i];
    half4v h;
    h[0] = (_Float16)v.x; h[1] = (_Float16)v.y;
    h[2] = (_Float16)v.z; h[3] = (_Float16)v.w;
    *(half4v*)(d + (size_t)i * 4) = h;
}

__global__ __launch_bounds__(256) void cvt16_kernel(
    const float* __restrict__ x_s, const float* __restrict__ x_t,
    const float* __restrict__ out_w, const float* __restrict__ in_w,
    const float* __restrict__ root_w, const float* __restrict__ rel_w,
    const int* __restrict__ dst_s, const int* __restrict__ dst_t,
    _Float16* __restrict__ x16, _Float16* __restrict__ outw16,
    _Float16* __restrict__ in16, _Float16* __restrict__ bt16,
    int* __restrict__ cnt)
{
    int gid = blockIdx.x * 256 + threadIdx.x, gs = gridDim.x * 256;
    const int nx = N_NODES * DIM / 4;
    const int nw = NLAYER * DIM * DIM / 4;
    const int ni = NLAYER * QDIM * DIM / 4;
    for (int i = gid; i < nx; i += gs) cvt4(x_s, x16, i);
    for (int i = gid; i < nx; i += gs) cvt4(x_t, x16 + N_NODES * DIM, i);
    for (int i = gid; i < nw; i += gs) cvt4(out_w, outw16, i);
    for (int i = gid; i < ni; i += gs) cvt4(in_w, in16, i);
    // transposed f16: bt16[L][m][k][j] = {root,rel}_w[L][j][k]
    const int nb = NLAYER * 2 * DIM * DIM;
    for (int i = gid; i < nb; i += gs) {
        int j = i & 127, k = (i >> 7) & 127, m = (i >> 14) & 1, L = i >> 15;
        const float* B = (m ? rel_w : root_w) + (size_t)L * DIM * DIM;
        bt16[i] = (_Float16)B[j * DIM + k];
    }
    for (int i = gid; i < 2 * NEDGE; i += gs) {
        int side = i >> 16, e = i & (NEDGE - 1);
        const int* dd = side ? dst_t : dst_s;
        atomicAdd(&cnt[side * N_NODES + dd[e]], 1);
    }
}

// ---------------- setup2: scan (blocks 0-1) + wfold MFMA (2-97) + beff (98-103)
__global__ __launch_bounds__(256) void setup2_kernel(
    const int* __restrict__ cnt, int* __restrict__ row_start, int* __restrict__ cursor,
    const _Float16* __restrict__ in16, const _Float16* __restrict__ bt16,
    _Float16* __restrict__ wq16,
    const float* __restrict__ in_w, const float* __restrict__ in_b,
    const float* __restrict__ rel_b, float* __restrict__ beff)
{
    int b = blockIdx.x;
    int t = threadIdx.x;
    if (b < 2) {
        // ---- exclusive scan ----
        int side = b;
        __shared__ int part[256];
        int local[16];
        int s = 0;
        #pragma unroll
        for (int j = 0; j < 16; ++j) { local[j] = cnt[side * N_NODES + t * 16 + j]; s += local[j]; }
        part[t] = s;
        __syncthreads();
        for (int off = 1; off < 256; off <<= 1) {
            int v = (t >= off) ? part[t - off] : 0;
            __syncthreads();
            part[t] += v;
            __syncthreads();
        }
        int run = (t == 0) ? 0 : part[t - 1];
        #pragma unroll
        for (int j = 0; j < 16; ++j) {
            int idx = t * 16 + j;
            row_start[side * (N_NODES + 1) + idx] = run;
            cursor[side * N_NODES + idx] = run;
            run += local[j];
        }
        if (t == 255) row_start[side * (N_NODES + 1) + N_NODES] = run;
    } else if (b < 98) {
        // ---- MFMA weight fold: wq16[L][m] = in16[L] @ bt16[L][m]^T ----
        int b2 = b - 2;
        int bx = b2 % 6;           // row tile (QDIM/64)
        int by = (b2 / 6) % 2;     // col tile (DIM/64)
        int lm = b2 / 12;          // L*2+m
        const _Float16* A = in16 + (size_t)(lm >> 1) * QDIM * DIM;
        const _Float16* B = bt16 + (size_t)lm * DIM * DIM;
        _Float16* C = wq16 + (size_t)lm * QDIM * DIM;
        int wave = t >> 6, lane = t & 63;
        int wm = wave >> 1, wn = wave & 1;
        int row0 = bx * 64 + wm * 32;
        int col0 = by * 64 + wn * 32;
        int lr = lane & 15;
        int lk = (lane >> 4) * 8;
        f32x4 zero = {0.f, 0.f, 0.f, 0.f};
        f32x4 acc[2][2] = {{zero, zero}, {zero, zero}};
        const _Float16* Ap0 = A + (size_t)(row0 + lr) * DIM + lk;
        const _Float16* Ap1 = A + (size_t)(row0 + 16 + lr) * DIM + lk;
        const _Float16* Bp0 = B + (size_t)(col0 + lr) * DIM + lk;
        const _Float16* Bp1 = B + (size_t)(col0 + 16 + lr) * DIM + lk;
        #pragma unroll
        for (int k0 = 0; k0 < DIM; k0 += 32) {
            half8v a0 = *(const half8v*)(Ap0 + k0);
            half8v a1 = *(const half8v*)(Ap1 + k0);
            half8v b0 = *(const half8v*)(Bp0 + k0);
            half8v b1 = *(const half8v*)(Bp1 + k0);
            acc[0][0] = MFMA(a0, b0, acc[0][0]);
            acc[0][1] = MFMA(a0, b1, acc[0][1]);
            acc[1][0] = MFMA(a1, b0, acc[1][0]);
            acc[1][1] = MFMA(a1, b1, acc[1][1]);
        }
        int g4 = (lane >> 4) * 4;
        #pragma unroll
        for (int fc = 0; fc < 2; ++fc) {
            int col = col0 + fc * 16 + lr;
            #pragma unroll
            for (int fr = 0; fr < 2; ++fr) {
                int rbase = row0 + fr * 16 + g4;
                #pragma unroll
                for (int j = 0; j < 4; ++j)
                    C[(size_t)(rbase + j) * DIM + col] = (_Float16)acc[fr][fc][j];
            }
        }
    } else {
        // ---- beff[L][384] = Win@brel + bin ----
        int gid = (b - 98) * 256 + t;
        if (gid >= NLAYER * QDIM) return;
        int L = gid / QDIM, i = gid % QDIM;
        const float* Win = in_w + (size_t)L * QDIM * DIM;
        const float* br = rel_b + (size_t)L * DIM;
        float s = in_b[(size_t)L * QDIM + i];
        #pragma unroll 4
        for (int j = 0; j < DIM; ++j) s += Win[(size_t)i * DIM + j] * br[j];
        beff[gid] = s;
    }
}

// ---------------- setup: fused reorder + gather (f16 sorted edge rows) --------
__global__ __launch_bounds__(256) void rg_kernel(
    const int* __restrict__ src_s, const int* __restrict__ dst_s,
    const int* __restrict__ src_t, const int* __restrict__ dst_t,
    const float* __restrict__ ea_s, const float* __restrict__ ea_t,
    int* __restrict__ cursor, int* __restrict__ srcs, _Float16* __restrict__ ea16s)
{
    int t = threadIdx.x;
    int g16 = t >> 4, sub = t & 15, lane = t & 63;
    int ef = blockIdx.x * 16 + g16;                  // [0, 2*NEDGE)
    int side = ef >> 16, e = ef & (NEDGE - 1);
    const int* dd = side ? dst_t : dst_s;
    const int* ss = side ? src_t : src_s;
    const float* ea = side ? ea_t : ea_s;
    int pos = 0;
    if (sub == 0) pos = atomicAdd(&cursor[side * N_NODES + dd[e]], 1);
    pos = __shfl(pos, lane & ~15);                   // broadcast within 16-group
    if (sub == 0) srcs[side * NEDGE + pos] = ss[e];
    const float* sp = ea + (size_t)e * DIM + sub * 8;
    float4 v0 = *(const float4*)(sp);
    float4 v1 = *(const float4*)(sp + 4);
    half8v h;
    h[0]=(_Float16)v0.x; h[1]=(_Float16)v0.y; h[2]=(_Float16)v0.z; h[3]=(_Float16)v0.w;
    h[4]=(_Float16)v1.x; h[5]=(_Float16)v1.y; h[6]=(_Float16)v1.z; h[7]=(_Float16)v1.w;
    *(half8v*)(ea16s + (size_t)(side * NEDGE + pos) * DIM + sub * 8) = h;
}

// ---------------- per-layer: CSR mean aggregate (1 wave/node, 2-edge split) --
// lanes 0-31 -> edge i, lanes 32-63 -> edge i+1; each lane half4 (4 dims).
__global__ __launch_bounds__(64) void agg_kernel(
    const int* __restrict__ srcs, const _Float16* __restrict__ ea16s,
    const int* __restrict__ row_start,
    const _Float16* __restrict__ x16, _Float16* __restrict__ agg16)
{
    int n = blockIdx.x, side = blockIdx.y;
    int lane = threadIdx.x;
    int half = lane >> 5;          // edge parity
    int sub = lane & 31;           // dim group [sub*4, sub*4+4)
    const int* sp = srcs + side * NEDGE;
    const _Float16* ep = ea16s + (size_t)side * NEDGE * DIM + sub * 4;
    const _Float16* xp = x16 + (size_t)side * N_NODES * DIM + sub * 4;
    int rs = row_start[side * (N_NODES + 1) + n];
    int re = row_start[side * (N_NODES + 1) + n + 1];
    float a0 = 0.f, a1 = 0.f, a2 = 0.f, a3 = 0.f;
    for (int i = rs + half; i < re; i += 2) {
        int s = sp[i];
        half4v w = *(const half4v*)(ep + (size_t)i * DIM);
        half4v xv = *(const half4v*)(xp + (size_t)s * DIM);
        a0 += (float)w[0] * (float)xv[0];
        a1 += (float)w[1] * (float)xv[1];
        a2 += (float)w[2] * (float)xv[2];
        a3 += (float)w[3] * (float)xv[3];
    }
    a0 += __shfl_xor(a0, 32);
    a1 += __shfl_xor(a1, 32);
    a2 += __shfl_xor(a2, 32);
    a3 += __shfl_xor(a3, 32);
    if (half == 0) {
        float sc = 1.0f / (float)max(re - rs, 1);
        half4v o;
        o[0] = (_Float16)(a0 * sc); o[1] = (_Float16)(a1 * sc);
        o[2] = (_Float16)(a2 * sc); o[3] = (_Float16)(a3 * sc);
        *(half4v*)(agg16 + (size_t)(side * N_NODES + n) * DIM + sub * 4) = o;
    }
}

// ---------------- per-layer: fused conv+qkv dual-source MFMA GEMM ----------
__global__ __launch_bounds__(256) void qkv2_mfma(
    const _Float16* __restrict__ x16, const _Float16* __restrict__ agg16,
    const _Float16* __restrict__ wq,     // [2][384][128] this layer
    const float* __restrict__ beff,      // [384]
    _Float16* __restrict__ qb16)
{
    int tid = threadIdx.x;
    int wave = tid >> 6, lane = tid & 63;
    int wm = wave >> 1, wn = wave & 1;
    int row0 = blockIdx.x * 64 + wm * 32;
    int col0 = blockIdx.y * 64 + wn * 32;
    int lr = lane & 15;
    int lk = (lane >> 4) * 8;
    f32x4 zero = {0.f, 0.f, 0.f, 0.f};
    f32x4 acc[2][2] = {{zero, zero}, {zero, zero}};
    #pragma unroll
    for (int s = 0; s < 2; ++s) {
        const _Float16* A = s ? agg16 : x16;
        const _Float16* W = wq + (size_t)s * QDIM * DIM;
        const _Float16* Ap0 = A + (size_t)(row0 + lr) * DIM + lk;
        const _Float16* Ap1 = A + (size_t)(row0 + 16 + lr) * DIM + lk;
        const _Float16* Wp0 = W + (size_t)(col0 + lr) * DIM + lk;
        const _Float16* Wp1 = W + (size_t)(col0 + 16 + lr) * DIM + lk;
        #pragma unroll
        for (int k0 = 0; k0 < DIM; k0 += 32) {
            half8v a0 = *(const half8v*)(Ap0 + k0);
            half8v a1 = *(const half8v*)(Ap1 + k0);
            half8v b0 = *(const half8v*)(Wp0 + k0);
            half8v b1 = *(const half8v*)(Wp1 + k0);
            acc[0][0] = MFMA(a0, b0, acc[0][0]);
            acc[0][1] = MFMA(a0, b1, acc[0][1]);
            acc[1][0] = MFMA(a1, b0, acc[1][0]);
            acc[1][1] = MFMA(a1, b1, acc[1][1]);
        }
    }
    int g4 = (lane >> 4) * 4;
    #pragma unroll
    for (int fc = 0; fc < 2; ++fc) {
        int col = col0 + fc * 16 + lr;
        float bv = beff[col];
        #pragma unroll
        for (int fr = 0; fr < 2; ++fr) {
            int rbase = row0 + fr * 16 + g4;
            #pragma unroll
            for (int j = 0; j < 4; ++j) {
                float v = acc[fr][fc][j] + bv;
                qb16[(size_t)(rbase + j) * QDIM + col] = (_Float16)v;
            }
        }
    }
}

// ---------------- per-layer: fused attention + out-proj + LayerNorm ----------
__global__ __launch_bounds__(256) void attn_oln_kernel(
    const _Float16* __restrict__ qkv, const _Float16* __restrict__ outw,
    const float* __restrict__ bias, const float* __restrict__ gamma,
    const float* __restrict__ beta, _Float16* __restrict__ x16out)
{
    int g = blockIdx.x, dir = blockIdx.y, rb = blockIdx.z;
    int qoff  = dir ? N_NODES : 0;
    int kvoff = dir ? 0 : N_NODES;
    int t = threadIdx.x;
    int w = t >> 6, lane = t & 63;         // wave w = head w
    int lr = lane & 15, g4 = lane >> 4;
    __shared__ _Float16 VT[NHEAD][32][136];   // V^T per head: [dim][key]
    __shared__ _Float16 P[NHEAD][16][136];    // normalized P per head (phase2: OL aliases P[0])
    __shared__ float red_s[16][5], red_q[16][5];
    f32x4 zero = {0.f, 0.f, 0.f, 0.f};
    // ---- stage V^T for head w (wave-private) ----
    for (int kk = lane; kk < 128; kk += 64) {
        const _Float16* vp = qkv + (size_t)(kvoff + g * 128 + kk) * QDIM + 2 * DIM + w * DHEAD;
        half8v v0 = *(const half8v*)(vp);
        half8v v1 = *(const half8v*)(vp + 8);
        half8v v2 = *(const half8v*)(vp + 16);
        half8v v3 = *(const half8v*)(vp + 24);
        #pragma unroll
        for (int j = 0; j < 8; ++j) {
            VT[w][j][kk]      = v0[j];
            VT[w][8 + j][kk]  = v1[j];
            VT[w][16 + j][kk] = v2[j];
            VT[w][24 + j][kk] = v3[j];
        }
    }
    // ---- QK^T from global fragments ----
    int qrow0 = qoff + g * 128 + rb * 16;
    const _Float16* qp = qkv + (size_t)(qrow0 + lr) * QDIM + w * DHEAD + g4 * 8;
    half8v qfrag = *(const half8v*)qp;
    f32x4 S[8];
    #pragma unroll
    for (int kf = 0; kf < 8; ++kf) {
        const _Float16* kp = qkv + (size_t)(kvoff + g * 128 + kf * 16 + lr) * QDIM
                             + DIM + w * DHEAD + g4 * 8;
        S[kf] = MFMA(qfrag, *(const half8v*)kp, zero);
    }
    // ---- wave-local softmax; normalized P -> LDS ----
    const float scale = 0.17677669529663687f;  // 1/sqrt(32)
    #pragma unroll
    for (int j = 0; j < 4; ++j) {
        float m = -INFINITY;
        #pragma unroll
        for (int kf = 0; kf < 8; ++kf) m = fmaxf(m, S[kf][j]);
        m *= scale;
        #pragma unroll
        for (int mk = 1; mk < 16; mk <<= 1) m = fmaxf(m, __shfl_xor(m, mk));
        float pj[8];
        float l = 0.f;
        #pragma unroll
        for (int kf = 0; kf < 8; ++kf) {
            float pv = __expf(S[kf][j] * scale - m);
            pj[kf] = pv; l += pv;
        }
        #pragma unroll
        for (int mk = 1; mk < 16; mk <<= 1) l += __shfl_xor(l, mk);
        float linv = 1.0f / l;
        int row = g4 * 4 + j;
        #pragma unroll
        for (int kf = 0; kf < 8; ++kf)
            P[w][row][kf * 16 + lr] = (_Float16)(pj[kf] * linv);
    }
    // ---- PV (wave-private LDS) ----
    f32x4 O[2] = {zero, zero};
    #pragma unroll
    for (int ks = 0; ks < 4; ++ks) {
        half8v pa = *(const half8v*)&P[w][lr][ks * 32 + g4 * 8];
        #pragma unroll
        for (int df = 0; df < 2; ++df) {
            half8v vb = *(const half8v*)&VT[w][df * 16 + lr][ks * 32 + g4 * 8];
            O[df] = MFMA(pa, vb, O[df]);
        }
    }
    __syncthreads();                            // all waves done with P before alias
    // ---- O -> LDS (OL aliases P[0]) ----
    _Float16 (*OL)[136] = P[0];
    #pragma unroll
    for (int df = 0; df < 2; ++df)
        #pragma unroll
        for (int j = 0; j < 4; ++j)
            OL[g4 * 4 + j][w * DHEAD + df * 16 + lr] = (_Float16)O[df][j];
    __syncthreads();
    // ---- out-proj: wave w computes cols [w*32, w*32+32) for all 16 rows ----
    f32x4 acc2[2] = {zero, zero};
    #pragma unroll
    for (int kk = 0; kk < 4; ++kk) {
        half8v a = *(const half8v*)&OL[lr][kk * 32 + g4 * 8];
        #pragma unroll
        for (int ct = 0; ct < 2; ++ct) {
            const _Float16* wp = outw + (size_t)(w * 32 + ct * 16 + lr) * DIM + kk * 32 + g4 * 8;
            acc2[ct] = MFMA(a, *(const half8v*)wp, acc2[ct]);
        }
    }
    // ---- bias + LayerNorm ----
    float v[2][4];
    #pragma unroll
    for (int ct = 0; ct < 2; ++ct) {
        float bv = bias[w * 32 + ct * 16 + lr];
        #pragma unroll
        for (int j = 0; j < 4; ++j) v[ct][j] = acc2[ct][j] + bv;
    }
    #pragma unroll
    for (int j = 0; j < 4; ++j) {
        float ss = v[0][j] + v[1][j];
        float qq = v[0][j] * v[0][j] + v[1][j] * v[1][j];
        #pragma unroll
        for (int mk = 1; mk < 16; mk <<= 1) {
            ss += __shfl_xor(ss, mk);
            qq += __shfl_xor(qq, mk);
        }
        if (lr == 0) {
            red_s[g4 * 4 + j][w] = ss;
            red_q[g4 * 4 + j][w] = qq;
        }
    }
    __syncthreads();
    #pragma unroll
    for (int j = 0; j < 4; ++j) {
        int row = g4 * 4 + j;
        float Sv = red_s[row][0] + red_s[row][1] + red_s[row][2] + red_s[row][3];
        float Qv = red_q[row][0] + red_q[row][1] + red_q[row][2] + red_q[row][3];
        float mu = Sv * (1.0f / 128.0f);
        float inv = rsqrtf(Qv * (1.0f / 128.0f) - mu * mu + 1e-5f);
        #pragma unroll
        for (int ct = 0; ct < 2; ++ct) {
            int col = w * 32 + ct * 16 + lr;
            float o = (v[ct][j] - mu) * inv * gamma[col] + beta[col];
            x16out[(size_t)(qrow0 + row) * DIM + col] = (_Float16)o;
        }
    }
}

// ---------------- pool + cosine ----------------
__global__ __launch_bounds__(256) void poolcos_kernel(
    const _Float16* __restrict__ x16, const float* __restrict__ gw,
    const float* __restrict__ gb, float* __restrict__ out)
{
    int g = blockIdx.x, t = threadIdx.x;
    int side = t >> 7, r = t & 127;
    __shared__ float sm[2][128];
    __shared__ float al[2][128];
    __shared__ float pl[2][DIM];
    const _Float16* xr = x16 + (size_t)(side * N_NODES + g * 128 + r) * DIM;
    float dot = gb[0];
    #pragma unroll
    for (int d = 0; d < DIM; d += 8) {
        half8v xv = *(const half8v*)(xr + d);
        #pragma unroll
        for (int u = 0; u < 8; ++u) dot += (float)xv[u] * gw[d + u];
    }
    float gate = 1.0f / (1.0f + __expf(-dot));
    sm[side][r] = gate; __syncthreads();
    for (int sN = 64; sN > 0; sN >>= 1) {
        if (r < sN) sm[side][r] = fmaxf(sm[side][r], sm[side][r + sN]);
        __syncthreads();
    }
    float m = sm[side][0]; __syncthreads();
    float e = __expf(gate - m);
    sm[side][r] = e; __syncthreads();
    for (int sN = 64; sN > 0; sN >>= 1) {
        if (r < sN) sm[side][r] += sm[side][r + sN];
        __syncthreads();
    }
    al[side][r] = e / sm[side][0];
    __syncthreads();
    int d = t & 127;
    float acc0 = 0.0f, acc1 = 0.0f, acc2 = 0.0f, acc3 = 0.0f;
    const _Float16* xg = x16 + (size_t)(side * N_NODES + g * 128) * DIM;
    #pragma unroll 4
    for (int n = 0; n < 128; n += 4) {
        acc0 += al[side][n]     * (float)xg[(size_t)n * DIM + d];
        acc1 += al[side][n + 1] * (float)xg[(size_t)(n + 1) * DIM + d];
        acc2 += al[side][n + 2] * (float)xg[(size_t)(n + 2) * DIM + d];
        acc3 += al[side][n + 3] * (float)xg[(size_t)(n + 3) * DIM + d];
    }
    pl[side][d] = (acc0 + acc1) + (acc2 + acc3);
    __syncthreads();
    if (t < 64) {
        float a0 = pl[0][t], a1 = pl[0][64 + t];
        float b0 = pl[1][t], b1 = pl[1][64 + t];
        float saa = a0 * a0 + a1 * a1;
        float sbb = b0 * b0 + b1 * b1;
        float sab = a0 * b0 + a1 * b1;
        #pragma unroll
        for (int off = 32; off; off >>= 1) {
            saa += __shfl_down(saa, off);
            sbb += __shfl_down(sbb, off);
            sab += __shfl_down(sab, off);
        }
        if (t == 0) {
            float na = fmaxf(sqrtf(saa), 1e-12f);
            float nb = fmaxf(sqrtf(sbb), 1e-12f);
            out[g] = sab / (na * nb);
        }
    }
}

extern "C" void kernel_launch(void* const* d_in, const int* in_sizes, int n_in,
                              void* d_out, int out_size, void* d_ws, size_t ws_size,
                              hipStream_t stream)
{
    const float* x_s    = (const float*)d_in[0];
    const float* x_t    = (const float*)d_in[1];
    const int*   ei_s   = (const int*)d_in[2];
    const float* ea_s   = (const float*)d_in[3];
    const int*   ei_t   = (const int*)d_in[4];
    const float* ea_t   = (const float*)d_in[5];
    const float* rel_w  = (const float*)d_in[8];
    const float* rel_b  = (const float*)d_in[9];
    const float* root_w = (const float*)d_in[10];
    const float* in_w   = (const float*)d_in[11];
    const float* in_b   = (const float*)d_in[12];
    const float* out_w  = (const float*)d_in[13];
    const float* out_b  = (const float*)d_in[14];
    const float* g_ln   = (const float*)d_in[15];
    const float* b_ln   = (const float*)d_in[16];
    const float* gate_w = (const float*)d_in[17];
    const float* gate_b = (const float*)d_in[18];
    float* out = (float*)d_out;

    const size_t RD = (size_t)NROWS * DIM;
    _Float16* h16p = (_Float16*)d_ws;
    _Float16* x16    = h16p; h16p += RD;
    _Float16* agg16  = h16p; h16p += RD;
    _Float16* qb16   = h16p; h16p += RD * 3;
    _Float16* ea16s  = h16p; h16p += (size_t)2 * NEDGE * DIM;
    _Float16* outw16 = h16p; h16p += (size_t)NLAYER * DIM * DIM;
    _Float16* wq16   = h16p; h16p += (size_t)NLAYER * 2 * QDIM * DIM;
    _Float16* in16   = h16p; h16p += (size_t)NLAYER * QDIM * DIM;
    _Float16* bt16   = h16p; h16p += (size_t)NLAYER * 2 * DIM * DIM;
    float* fws = (float*)h16p;
    float* beff = fws; fws += NLAYER * QDIM;
    int* iws = (int*)fws;
    int* cnt       = iws; iws += 2 * N_NODES;
    int* cursor    = iws; iws += 2 * N_NODES;
    int* row_start = iws; iws += 2 * (N_NODES + 1);
    int* srcs      = iws; iws += 2 * NEDGE;

    const int* src_s = ei_s, *dst_s = ei_s + NEDGE;
    const int* src_t = ei_t, *dst_t = ei_t + NEDGE;

    // setup
    hipMemsetAsync(cnt, 0, 2 * N_NODES * 4, stream);
    cvt16_kernel<<<512, 256, 0, stream>>>(x_s, x_t, out_w, in_w, root_w, rel_w,
                                          dst_s, dst_t, x16, outw16, in16, bt16, cnt);
    setup2_kernel<<<104, 256, 0, stream>>>(cnt, row_start, cursor, in16, bt16, wq16,
                                           in_w, in_b, rel_b, beff);
    rg_kernel<<<2 * NEDGE / 16, 256, 0, stream>>>(src_s, dst_s, src_t, dst_t,
                                                  ea_s, ea_t, cursor, srcs, ea16s);

    dim3 gq(NROWS / 64, QDIM / 64);   // 128 x 6
    dim3 gagg(N_NODES, 2);
    dim3 gattn(BGRAPH, 2, 8);          // 512 blocks

    for (int i = 0; i < NLAYER; ++i) {
        const _Float16* wq   = wq16   + (size_t)i * 2 * QDIM * DIM;
        const float*    be   = beff   + (size_t)i * QDIM;
        const _Float16* wout = outw16 + (size_t)i * DIM * DIM;
        const float*    bout = out_b  + (size_t)i * DIM;
        const float*    lg   = g_ln   + (size_t)i * DIM;
        const float*    lb   = b_ln   + (size_t)i * DIM;

        agg_kernel<<<gagg, 64, 0, stream>>>(srcs, ea16s, row_start, x16, agg16);
        qkv2_mfma<<<gq, 256, 0, stream>>>(x16, agg16, wq, be, qb16);
        attn_oln_kernel<<<gattn, 256, 0, stream>>>(qb16, wout, bout, lg, lb, x16);
    }

    poolcos_kernel<<<BGRAPH, 256, 0, stream>>>(x16, gate_w, gate_b, out);
}